// Round 1
// baseline (13314.879 us; speedup 1.0000x reference)
//
#include <hip/hip_runtime.h>

#define NN 50000
#define DD 256
#define NT 3
#define NL 4
#define EPT 300000

// ---------------- gather: h[i] = emb[labels[i]] ----------------
__global__ void gather_emb(const int* __restrict__ labels,
                           const float* __restrict__ emb,
                           float* __restrict__ h) {
  int node = blockIdx.x;
  int lane = threadIdx.x;  // 0..63, each handles one float4
  float4 v = ((const float4*)(emb + (size_t)labels[node] * DD))[lane];
  ((float4*)(h + (size_t)node * DD))[lane] = v;
}

// ---------------- zero a float buffer (graph-capture-safe memset) ----------------
__global__ void zero_kernel(float* __restrict__ p, int n) {
  int i = blockIdx.x * blockDim.x + threadIdx.x;
  int stride = gridDim.x * blockDim.x;
  float4* p4 = (float4*)p;
  int n4 = n >> 2;
  for (; i < n4; i += stride) p4[i] = make_float4(0.f, 0.f, 0.f, 0.f);
}

// ---------------- scatter: G[tgt] += h[src] over edges ----------------
__global__ __launch_bounds__(256) void scatter_add(
    const int* __restrict__ adj,  // [EPT][2]
    const float* __restrict__ h,
    float* __restrict__ G) {
  int tid = blockIdx.x * 256 + threadIdx.x;
  int e = tid >> 6;           // edge index (wave-uniform)
  if (e >= EPT) return;
  int lane = tid & 63;
  int s = adj[2 * e];
  int t = adj[2 * e + 1];
  float4 v = ((const float4*)(h + (size_t)s * DD))[lane];
  float* gp = G + (size_t)t * DD + (lane << 2);
  atomicAdd(gp + 0, v.x);
  atomicAdd(gp + 1, v.y);
  atomicAdd(gp + 2, v.z);
  atomicAdd(gp + 3, v.w);
}

// ---------------- fp32 GEMM: C (+)= A @ W, optional ReLU epilogue ----------------
// A: [M][256] row-major, W: [256][256] row-major, C: [M][256]
// 64x64 output tile per block, 256 threads, 4x4 register tile per thread.
template <int BETA, int RELU>
__global__ __launch_bounds__(256) void gemm_tile(
    const float* __restrict__ A,
    const float* __restrict__ W,
    float* __restrict__ C,
    int M) {
  __shared__ float As[16][68];  // As[k][m], padded stride 68 floats (272B, 16B-aligned)
  __shared__ float Bs[16][64];  // Bs[k][n]

  const int tid = threadIdx.x;
  const int m0 = blockIdx.x * 64;
  const int n0 = blockIdx.y * 64;
  const int tm = (tid & 15) * 4;
  const int tn = (tid >> 4) * 4;

  // A-tile load mapping: each thread loads float4 along k
  const int lm = tid >> 2;        // 0..63
  const int lk = (tid & 3) * 4;   // 0,4,8,12
  // B-tile load mapping
  const int bk = tid >> 4;        // 0..15
  const int bn = (tid & 15) * 4;  // 0..60

  float acc[4][4] = {{0.f, 0.f, 0.f, 0.f},
                     {0.f, 0.f, 0.f, 0.f},
                     {0.f, 0.f, 0.f, 0.f},
                     {0.f, 0.f, 0.f, 0.f}};

  for (int kk = 0; kk < DD; kk += 16) {
    float4 av;
    int gm = m0 + lm;
    if (gm < M)
      av = *(const float4*)(A + (size_t)gm * DD + kk + lk);
    else
      av = make_float4(0.f, 0.f, 0.f, 0.f);
    As[lk + 0][lm] = av.x;
    As[lk + 1][lm] = av.y;
    As[lk + 2][lm] = av.z;
    As[lk + 3][lm] = av.w;

    *(float4*)(&Bs[bk][bn]) = *(const float4*)(W + (size_t)(kk + bk) * DD + n0 + bn);

    __syncthreads();

#pragma unroll
    for (int k = 0; k < 16; ++k) {
      float4 a = *(const float4*)(&As[k][tm]);
      float4 b = *(const float4*)(&Bs[k][tn]);
      acc[0][0] = fmaf(a.x, b.x, acc[0][0]);
      acc[0][1] = fmaf(a.x, b.y, acc[0][1]);
      acc[0][2] = fmaf(a.x, b.z, acc[0][2]);
      acc[0][3] = fmaf(a.x, b.w, acc[0][3]);
      acc[1][0] = fmaf(a.y, b.x, acc[1][0]);
      acc[1][1] = fmaf(a.y, b.y, acc[1][1]);
      acc[1][2] = fmaf(a.y, b.z, acc[1][2]);
      acc[1][3] = fmaf(a.y, b.w, acc[1][3]);
      acc[2][0] = fmaf(a.z, b.x, acc[2][0]);
      acc[2][1] = fmaf(a.z, b.y, acc[2][1]);
      acc[2][2] = fmaf(a.z, b.z, acc[2][2]);
      acc[2][3] = fmaf(a.z, b.w, acc[2][3]);
      acc[3][0] = fmaf(a.w, b.x, acc[3][0]);
      acc[3][1] = fmaf(a.w, b.y, acc[3][1]);
      acc[3][2] = fmaf(a.w, b.z, acc[3][2]);
      acc[3][3] = fmaf(a.w, b.w, acc[3][3]);
    }
    __syncthreads();
  }

#pragma unroll
  for (int i = 0; i < 4; ++i) {
    int row = m0 + tm + i;
    if (row >= M) continue;
    float* cp = C + (size_t)row * DD + n0 + tn;
    float4 r = make_float4(acc[i][0], acc[i][1], acc[i][2], acc[i][3]);
    if (BETA) {
      float4 c = *(const float4*)cp;
      r.x += c.x;
      r.y += c.y;
      r.z += c.z;
      r.w += c.w;
    }
    if (RELU) {
      r.x = fmaxf(r.x, 0.f);
      r.y = fmaxf(r.y, 0.f);
      r.z = fmaxf(r.z, 0.f);
      r.w = fmaxf(r.w, 0.f);
    }
    *(float4*)cp = r;
  }
}

extern "C" void kernel_launch(void* const* d_in, const int* in_sizes, int n_in,
                              void* d_out, int out_size, void* d_ws, size_t ws_size,
                              hipStream_t stream) {
  const int* labels = (const int*)d_in[0];
  const int* adj = (const int*)d_in[1];      // [NT][EPT][2]
  const float* emb = (const float*)d_in[2];  // [VOCAB][DD]
  const float* Wl = (const float*)d_in[3];   // [NL][NT][DD][DD]
  float* out = (float*)d_out;

  const size_t hbytes = (size_t)NN * DD;  // elements
  float* G = (float*)d_ws;
  float* hbuf = (float*)((char*)d_ws + hbytes * sizeof(float));

  // h0 -> d_out (buffer 0); layers ping-pong: out->hbuf->out->hbuf->out
  gather_emb<<<NN, 64, 0, stream>>>(labels, emb, out);

  for (int l = 0; l < NL; ++l) {
    const float* hin = (l & 1) ? hbuf : out;
    float* hout = (l & 1) ? out : hbuf;
    // NOTE: layer count is even, so final write lands in d_out:
    // l0: out->hbuf, l1: hbuf->out, l2: out->hbuf, l3: hbuf->out
    for (int t = 0; t < NT; ++t) {
      zero_kernel<<<2048, 256, 0, stream>>>(G, NN * DD);
      scatter_add<<<(EPT * 64) / 256, 256, 0, stream>>>(adj + (size_t)t * EPT * 2, hin, G);
      const float* W = Wl + ((size_t)(l * NT + t)) * DD * DD;
      dim3 grid((NN + 63) / 64, DD / 64);
      if (t == 0)
        gemm_tile<0, 0><<<grid, 256, 0, stream>>>(G, W, hout, NN);
      else if (t == 1)
        gemm_tile<1, 0><<<grid, 256, 0, stream>>>(G, W, hout, NN);
      else
        gemm_tile<1, 1><<<grid, 256, 0, stream>>>(G, W, hout, NN);
    }
  }
}

// Round 3
// 1879.362 us; speedup vs baseline: 7.0848x; 7.0848x over previous
//
#include <hip/hip_runtime.h>

#define NN 50000
#define DD 256
#define NT 3
#define NL 4
#define EPT 300000
#define SCAN_BLOCKS 196  // ceil(50000/256)

// ---------------- gather: h[i] = emb[labels[i]] ----------------
__global__ void gather_emb(const int* __restrict__ labels,
                           const float* __restrict__ emb,
                           float* __restrict__ h) {
  int node = blockIdx.x;
  int lane = threadIdx.x;  // 0..63, one float4 each
  float4 v = ((const float4*)(emb + (size_t)labels[node] * DD))[lane];
  ((float4*)(h + (size_t)node * DD))[lane] = v;
}

// ---------------- zero buffer (graph-capture-safe) ----------------
__global__ void zero_kernel(float* __restrict__ p, int n4) {
  int i = blockIdx.x * blockDim.x + threadIdx.x;
  int stride = gridDim.x * blockDim.x;
  float4* p4 = (float4*)p;
  for (; i < n4; i += stride) p4[i] = make_float4(0.f, 0.f, 0.f, 0.f);
}

// ---------------- CSR build ----------------
__global__ __launch_bounds__(256) void hist_kernel(const int* __restrict__ adj,
                                                   int* __restrict__ counts) {
  int t = blockIdx.y;
  int e = blockIdx.x * 256 + threadIdx.x;
  if (e >= EPT) return;
  int tgt = adj[(size_t)t * EPT * 2 + 2 * e + 1];
  atomicAdd(&counts[t * NN + tgt], 1);
}

__global__ __launch_bounds__(256) void scan1(const int* __restrict__ counts,
                                             int* __restrict__ rowptr,
                                             int* __restrict__ bsums) {
  int t = blockIdx.y, b = blockIdx.x;
  int i = b * 256 + threadIdx.x;
  int v = (i < NN) ? counts[t * NN + i] : 0;
  __shared__ int s[256];
  s[threadIdx.x] = v;
  __syncthreads();
  for (int off = 1; off < 256; off <<= 1) {
    int y = (threadIdx.x >= off) ? s[threadIdx.x - off] : 0;
    __syncthreads();
    s[threadIdx.x] += y;
    __syncthreads();
  }
  if (i < NN) rowptr[t * (NN + 1) + i] = s[threadIdx.x] - v;  // exclusive
  if (threadIdx.x == 255) bsums[t * SCAN_BLOCKS + b] = s[255];
}

__global__ __launch_bounds__(256) void scan2(int* __restrict__ bsums) {
  int t = blockIdx.x;
  int v = (threadIdx.x < SCAN_BLOCKS) ? bsums[t * SCAN_BLOCKS + threadIdx.x] : 0;
  __shared__ int s[256];
  s[threadIdx.x] = v;
  __syncthreads();
  for (int off = 1; off < 256; off <<= 1) {
    int y = (threadIdx.x >= off) ? s[threadIdx.x - off] : 0;
    __syncthreads();
    s[threadIdx.x] += y;
    __syncthreads();
  }
  if (threadIdx.x < SCAN_BLOCKS) bsums[t * SCAN_BLOCKS + threadIdx.x] = s[threadIdx.x] - v;
}

__global__ __launch_bounds__(256) void scan3(int* __restrict__ rowptr,
                                             const int* __restrict__ bsums,
                                             int* __restrict__ cursor) {
  int t = blockIdx.y, b = blockIdx.x;
  int i = b * 256 + threadIdx.x;
  if (i < NN) {
    int r = rowptr[t * (NN + 1) + i] + bsums[t * SCAN_BLOCKS + b];
    rowptr[t * (NN + 1) + i] = r;
    cursor[t * NN + i] = r;
  }
  if (b == 0 && threadIdx.x == 0) rowptr[t * (NN + 1) + NN] = EPT;
}

__global__ __launch_bounds__(256) void bucket_kernel(const int* __restrict__ adj,
                                                     int* __restrict__ cursor,
                                                     int* __restrict__ esrc) {
  int t = blockIdx.y;
  int e = blockIdx.x * 256 + threadIdx.x;
  if (e >= EPT) return;
  int s = adj[(size_t)t * EPT * 2 + 2 * e];
  int tgt = adj[(size_t)t * EPT * 2 + 2 * e + 1];
  int pos = atomicAdd(&cursor[t * NN + tgt], 1);
  esrc[(size_t)t * EPT + pos] = s;
}

// ---------------- aggregation: G[n] = sum_{e in in(n)} h[src(e)] ----------------
__global__ __launch_bounds__(256) void agg_csr(const int* __restrict__ rowptr,
                                               const int* __restrict__ esrc,
                                               const float* __restrict__ h,
                                               float* __restrict__ G) {
  int node = blockIdx.x * 4 + (threadIdx.x >> 6);
  if (node >= NN) return;
  int lane = threadIdx.x & 63;
  int beg = rowptr[node];
  int end = rowptr[node + 1];
  const float4* h4 = (const float4*)h;
  float4 acc = make_float4(0.f, 0.f, 0.f, 0.f);
  int e = beg;
  for (; e + 1 < end; e += 2) {
    int s0 = esrc[e];
    int s1 = esrc[e + 1];
    float4 v0 = h4[(size_t)s0 * 64 + lane];
    float4 v1 = h4[(size_t)s1 * 64 + lane];
    acc.x += v0.x + v1.x;
    acc.y += v0.y + v1.y;
    acc.z += v0.z + v1.z;
    acc.w += v0.w + v1.w;
  }
  if (e < end) {
    int s0 = esrc[e];
    float4 v0 = h4[(size_t)s0 * 64 + lane];
    acc.x += v0.x;
    acc.y += v0.y;
    acc.z += v0.z;
    acc.w += v0.w;
  }
  ((float4*)G)[(size_t)node * 64 + lane] = acc;
}

// ---------------- fp32 GEMM: C (+)= A @ W, optional ReLU ----------------
template <int BETA, int RELU>
__global__ __launch_bounds__(256) void gemm_tile(
    const float* __restrict__ A,
    const float* __restrict__ W,
    float* __restrict__ C,
    int M) {
  __shared__ float As[16][68];
  __shared__ float Bs[16][64];

  const int tid = threadIdx.x;
  const int m0 = blockIdx.x * 64;
  const int n0 = blockIdx.y * 64;
  const int tm = (tid & 15) * 4;
  const int tn = (tid >> 4) * 4;

  const int lm = tid >> 2;
  const int lk = (tid & 3) * 4;
  const int bk = tid >> 4;
  const int bn = (tid & 15) * 4;

  float acc[4][4] = {{0.f, 0.f, 0.f, 0.f},
                     {0.f, 0.f, 0.f, 0.f},
                     {0.f, 0.f, 0.f, 0.f},
                     {0.f, 0.f, 0.f, 0.f}};

  for (int kk = 0; kk < DD; kk += 16) {
    float4 av;
    int gm = m0 + lm;
    if (gm < M)
      av = *(const float4*)(A + (size_t)gm * DD + kk + lk);
    else
      av = make_float4(0.f, 0.f, 0.f, 0.f);
    As[lk + 0][lm] = av.x;
    As[lk + 1][lm] = av.y;
    As[lk + 2][lm] = av.z;
    As[lk + 3][lm] = av.w;

    *(float4*)(&Bs[bk][bn]) = *(const float4*)(W + (size_t)(kk + bk) * DD + n0 + bn);

    __syncthreads();

#pragma unroll
    for (int k = 0; k < 16; ++k) {
      float4 a = *(const float4*)(&As[k][tm]);
      float4 b = *(const float4*)(&Bs[k][tn]);
      acc[0][0] = fmaf(a.x, b.x, acc[0][0]);
      acc[0][1] = fmaf(a.x, b.y, acc[0][1]);
      acc[0][2] = fmaf(a.x, b.z, acc[0][2]);
      acc[0][3] = fmaf(a.x, b.w, acc[0][3]);
      acc[1][0] = fmaf(a.y, b.x, acc[1][0]);
      acc[1][1] = fmaf(a.y, b.y, acc[1][1]);
      acc[1][2] = fmaf(a.y, b.z, acc[1][2]);
      acc[1][3] = fmaf(a.y, b.w, acc[1][3]);
      acc[2][0] = fmaf(a.z, b.x, acc[2][0]);
      acc[2][1] = fmaf(a.z, b.y, acc[2][1]);
      acc[2][2] = fmaf(a.z, b.z, acc[2][2]);
      acc[2][3] = fmaf(a.z, b.w, acc[2][3]);
      acc[3][0] = fmaf(a.w, b.x, acc[3][0]);
      acc[3][1] = fmaf(a.w, b.y, acc[3][1]);
      acc[3][2] = fmaf(a.w, b.z, acc[3][2]);
      acc[3][3] = fmaf(a.w, b.w, acc[3][3]);
    }
    __syncthreads();
  }

#pragma unroll
  for (int i = 0; i < 4; ++i) {
    int row = m0 + tm + i;
    if (row >= M) continue;
    float* cp = C + (size_t)row * DD + n0 + tn;
    float4 r = make_float4(acc[i][0], acc[i][1], acc[i][2], acc[i][3]);
    if (BETA) {
      float4 c = *(const float4*)cp;
      r.x += c.x;
      r.y += c.y;
      r.z += c.z;
      r.w += c.w;
    }
    if (RELU) {
      r.x = fmaxf(r.x, 0.f);
      r.y = fmaxf(r.y, 0.f);
      r.z = fmaxf(r.z, 0.f);
      r.w = fmaxf(r.w, 0.f);
    }
    *(float4*)cp = r;
  }
}

extern "C" void kernel_launch(void* const* d_in, const int* in_sizes, int n_in,
                              void* d_out, int out_size, void* d_ws, size_t ws_size,
                              hipStream_t stream) {
  const int* labels = (const int*)d_in[0];
  const int* adj = (const int*)d_in[1];      // [NT][EPT][2]
  const float* emb = (const float*)d_in[2];  // [VOCAB][DD]
  const float* Wl = (const float*)d_in[3];   // [NL][NT][DD][DD]
  float* out = (float*)d_out;

  // ---- workspace layout ----
  // [0, 51.2MB)   : G (fp32 NN*DD) -- overlaid by counts/cursor/bsums during CSR build
  // [51.2,102.4MB): hbuf (fp32 NN*DD)
  // [102.4MB ...) : rowptr (3*(NN+1) int), esrc (3*EPT int)
  char* base = (char*)d_ws;
  float* G = (float*)base;
  float* hbuf = (float*)(base + (size_t)NN * DD * sizeof(float));
  int* rowptr = (int*)(base + 2 * (size_t)NN * DD * sizeof(float));
  int* esrc = (int*)((char*)rowptr + ((3 * (NN + 1) + 3) & ~3) * sizeof(int));
  // build-time temporaries overlaid on G (G not live until first agg):
  int* counts = (int*)G;                           // 3*NN ints (600KB)
  int* cursor = (int*)((char*)G + (1 << 20));      // at +1MB
  int* bsums = (int*)((char*)G + (2 << 20));       // at +2MB

  // ---- h0 = emb[labels] -> d_out ----
  gather_emb<<<NN, 64, 0, stream>>>(labels, emb, out);

  // ---- CSR build (once; adjacency shared by all layers) ----
  zero_kernel<<<256, 256, 0, stream>>>((float*)counts, (3 * NN) / 4);
  {
    dim3 g((EPT + 255) / 256, NT);
    hist_kernel<<<g, 256, 0, stream>>>(adj, counts);
  }
  {
    dim3 g(SCAN_BLOCKS, NT);
    scan1<<<g, 256, 0, stream>>>(counts, rowptr, bsums);
  }
  scan2<<<NT, 256, 0, stream>>>(bsums);
  {
    dim3 g(SCAN_BLOCKS, NT);
    scan3<<<g, 256, 0, stream>>>(rowptr, bsums, cursor);
  }
  {
    dim3 g((EPT + 255) / 256, NT);
    bucket_kernel<<<g, 256, 0, stream>>>(adj, cursor, esrc);
  }

  // ---- layers: ping-pong out -> hbuf -> out -> hbuf -> out ----
  for (int l = 0; l < NL; ++l) {
    const float* hin = (l & 1) ? hbuf : out;
    float* hout = (l & 1) ? out : hbuf;
    for (int t = 0; t < NT; ++t) {
      agg_csr<<<(NN + 3) / 4, 256, 0, stream>>>(
          rowptr + (size_t)t * (NN + 1), esrc + (size_t)t * EPT, hin, G);
      const float* W = Wl + ((size_t)(l * NT + t)) * DD * DD;
      dim3 grid((NN + 63) / 64, DD / 64);
      if (t == 0)
        gemm_tile<0, 0><<<grid, 256, 0, stream>>>(G, W, hout, NN);
      else if (t == 1)
        gemm_tile<1, 0><<<grid, 256, 0, stream>>>(G, W, hout, NN);
      else
        gemm_tile<1, 1><<<grid, 256, 0, stream>>>(G, W, hout, NN);
    }
  }
}

// Round 4
// 862.750 us; speedup vs baseline: 15.4331x; 2.1783x over previous
//
#include <hip/hip_runtime.h>

#define NN 50000
#define DD 256
#define NT 3
#define NL 4
#define EPT 300000
#define KK 768               // 3*DD concatenated-K
#define SCAN_BLOCKS 196      // ceil(50000/256)
#define MROWS 50048          // Gcat rows padded to 128-tile multiple

typedef __attribute__((ext_vector_type(8))) short bf16x8;
typedef __attribute__((ext_vector_type(4))) float f32x4;

__device__ __forceinline__ unsigned short f2bf(float f) {
  unsigned u = __builtin_bit_cast(unsigned, f);
  unsigned r = u + 0x7fffu + ((u >> 16) & 1u);  // RNE
  return (unsigned short)(r >> 16);
}
__device__ __forceinline__ float bflo2f(unsigned u) {
  return __builtin_bit_cast(float, u << 16);
}
__device__ __forceinline__ float bfhi2f(unsigned u) {
  return __builtin_bit_cast(float, u & 0xffff0000u);
}

// ---------------- h0[i] = bf16(emb[labels[i]]) ----------------
__global__ void gather_emb(const int* __restrict__ labels,
                           const float* __restrict__ emb,
                           unsigned short* __restrict__ h) {
  int node = blockIdx.x;
  int lane = threadIdx.x;  // 0..63
  float4 v = ((const float4*)(emb + (size_t)labels[node] * DD))[lane];
  unsigned a = (unsigned)f2bf(v.x) | ((unsigned)f2bf(v.y) << 16);
  unsigned b = (unsigned)f2bf(v.z) | ((unsigned)f2bf(v.w) << 16);
  ((uint2*)(h + (size_t)node * DD))[lane] = make_uint2(a, b);
}

// ---------------- zero buffer (graph-capture-safe) ----------------
__global__ void zero_kernel(float* __restrict__ p, int n4) {
  int i = blockIdx.x * blockDim.x + threadIdx.x;
  int stride = gridDim.x * blockDim.x;
  float4* p4 = (float4*)p;
  for (; i < n4; i += stride) p4[i] = make_float4(0.f, 0.f, 0.f, 0.f);
}

// ---------------- W -> bf16, transposed+concatenated: WT[l][n][t*256+k] ----------------
__global__ __launch_bounds__(256) void wconv(const float* __restrict__ Wl,
                                             unsigned short* __restrict__ WT) {
  int i = blockIdx.x * 256 + threadIdx.x;  // < NL*DD*KK
  int l = i / (DD * KK);
  int rem = i % (DD * KK);
  int n = rem / KK;
  int kk = rem % KK;
  int t = kk >> 8;
  int k = kk & 255;
  float v = Wl[((size_t)(l * NT + t) * DD + k) * DD + n];
  WT[i] = f2bf(v);
}

// ---------------- CSR build ----------------
__global__ __launch_bounds__(256) void hist_kernel(const int* __restrict__ adj,
                                                   int* __restrict__ counts) {
  int t = blockIdx.y;
  int e = blockIdx.x * 256 + threadIdx.x;
  if (e >= EPT) return;
  int tgt = adj[(size_t)t * EPT * 2 + 2 * e + 1];
  atomicAdd(&counts[t * NN + tgt], 1);
}

__global__ __launch_bounds__(256) void scan1(const int* __restrict__ counts,
                                             int* __restrict__ rowptr,
                                             int* __restrict__ bsums) {
  int t = blockIdx.y, b = blockIdx.x;
  int i = b * 256 + threadIdx.x;
  int v = (i < NN) ? counts[t * NN + i] : 0;
  __shared__ int s[256];
  s[threadIdx.x] = v;
  __syncthreads();
  for (int off = 1; off < 256; off <<= 1) {
    int y = (threadIdx.x >= off) ? s[threadIdx.x - off] : 0;
    __syncthreads();
    s[threadIdx.x] += y;
    __syncthreads();
  }
  if (i < NN) rowptr[t * (NN + 1) + i] = s[threadIdx.x] - v;  // exclusive
  if (threadIdx.x == 255) bsums[t * SCAN_BLOCKS + b] = s[255];
}

__global__ __launch_bounds__(256) void scan2(int* __restrict__ bsums) {
  int t = blockIdx.x;
  int v = (threadIdx.x < SCAN_BLOCKS) ? bsums[t * SCAN_BLOCKS + threadIdx.x] : 0;
  __shared__ int s[256];
  s[threadIdx.x] = v;
  __syncthreads();
  for (int off = 1; off < 256; off <<= 1) {
    int y = (threadIdx.x >= off) ? s[threadIdx.x - off] : 0;
    __syncthreads();
    s[threadIdx.x] += y;
    __syncthreads();
  }
  if (threadIdx.x < SCAN_BLOCKS) bsums[t * SCAN_BLOCKS + threadIdx.x] = s[threadIdx.x] - v;
}

__global__ __launch_bounds__(256) void scan3(int* __restrict__ rowptr,
                                             const int* __restrict__ bsums,
                                             int* __restrict__ cursor) {
  int t = blockIdx.y, b = blockIdx.x;
  int i = b * 256 + threadIdx.x;
  if (i < NN) {
    int r = rowptr[t * (NN + 1) + i] + bsums[t * SCAN_BLOCKS + b];
    rowptr[t * (NN + 1) + i] = r;
    cursor[t * NN + i] = r;
  }
  if (b == 0 && threadIdx.x == 0) rowptr[t * (NN + 1) + NN] = EPT;
}

__global__ __launch_bounds__(256) void bucket_kernel(const int* __restrict__ adj,
                                                     int* __restrict__ cursor,
                                                     int* __restrict__ esrc) {
  int t = blockIdx.y;
  int e = blockIdx.x * 256 + threadIdx.x;
  if (e >= EPT) return;
  int s = adj[(size_t)t * EPT * 2 + 2 * e];
  int tgt = adj[(size_t)t * EPT * 2 + 2 * e + 1];
  int pos = atomicAdd(&cursor[t * NN + tgt], 1);
  esrc[(size_t)t * EPT + pos] = s;
}

// ---------------- agg: Gcat[n][t*256..] = bf16( sum_{e in(n)} h[src(e)] ) ----------------
__global__ __launch_bounds__(256) void agg_csr(const int* __restrict__ rowptr,
                                               const int* __restrict__ esrc,
                                               const unsigned short* __restrict__ h,
                                               unsigned short* __restrict__ Gcat, int t) {
  int node = blockIdx.x * 4 + (threadIdx.x >> 6);
  if (node >= NN) return;
  int lane = threadIdx.x & 63;
  int beg = rowptr[node];
  int end = rowptr[node + 1];
  const uint2* h2 = (const uint2*)h;
  float a0 = 0.f, a1 = 0.f, a2 = 0.f, a3 = 0.f;
  int e = beg;
  for (; e + 1 < end; e += 2) {
    uint2 v0 = h2[(size_t)esrc[e] * 64 + lane];
    uint2 v1 = h2[(size_t)esrc[e + 1] * 64 + lane];
    a0 += bflo2f(v0.x) + bflo2f(v1.x);
    a1 += bfhi2f(v0.x) + bfhi2f(v1.x);
    a2 += bflo2f(v0.y) + bflo2f(v1.y);
    a3 += bfhi2f(v0.y) + bfhi2f(v1.y);
  }
  if (e < end) {
    uint2 v0 = h2[(size_t)esrc[e] * 64 + lane];
    a0 += bflo2f(v0.x);
    a1 += bfhi2f(v0.x);
    a2 += bflo2f(v0.y);
    a3 += bfhi2f(v0.y);
  }
  unsigned pa = (unsigned)f2bf(a0) | ((unsigned)f2bf(a1) << 16);
  unsigned pb = (unsigned)f2bf(a2) | ((unsigned)f2bf(a3) << 16);
  ((uint2*)(Gcat + (size_t)node * KK + t * DD))[lane] = make_uint2(pa, pb);
}

// ---------------- bf16 MFMA GEMM: C = relu(A[M][768] @ WT^T), N=256 ----------------
// A row-major bf16 (lda=KK), BT = WT[l]: [256][768] bf16 (B transposed), 128x128 tile,
// BK=64, 4 waves of 64x64, 16x16x32 MFMA, XOR-swizzled LDS (T2).
template <int OUTF32>
__global__ __launch_bounds__(256) void gemm_bf16(const unsigned short* __restrict__ A,
                                                 const unsigned short* __restrict__ BT,
                                                 void* __restrict__ Cout, int M) {
  __shared__ __align__(16) char lds[2 * 32768];  // [A 16KB | B 16KB] x 2 buffers
  const int tid = threadIdx.x;
  const int m0 = blockIdx.x * 128;
  const int n0 = blockIdx.y * 128;
  const int w = tid >> 6, lane = tid & 63;
  const int wm = (w >> 1) * 64, wn = (w & 1) * 64;
  const int r15 = lane & 15, g16 = (lane >> 4) * 16;

  f32x4 acc[4][4] = {};

  uint4 ra[4], rb[4];
  const char* Ab = (const char*)A;
  const char* Bb = (const char*)BT;

  const int NTK = KK / 64;  // 12 k-steps

#define GLOAD(kt)                                                              \
  {                                                                            \
    size_t kb = (size_t)(kt) * 128;                                            \
    _Pragma("unroll") for (int p = 0; p < 4; p++) {                            \
      int lin = p * 4096 + tid * 16;                                           \
      int row = lin >> 7, colB = lin & 127;                                    \
      ra[p] = *(const uint4*)(Ab + (size_t)(m0 + row) * (KK * 2) + kb + colB); \
      rb[p] = *(const uint4*)(Bb + (size_t)(n0 + row) * (KK * 2) + kb + colB); \
    }                                                                          \
  }
#define SWRITE(buf)                                            \
  {                                                            \
    char* sb = lds + (buf) * 32768;                            \
    _Pragma("unroll") for (int p = 0; p < 4; p++) {            \
      int lin = p * 4096 + tid * 16;                           \
      int row = lin >> 7, colB = lin & 127;                    \
      int sc = colB ^ ((row & 7) << 4);                        \
      *(uint4*)(sb + row * 128 + sc) = ra[p];                  \
      *(uint4*)(sb + 16384 + row * 128 + sc) = rb[p];          \
    }                                                          \
  }

  GLOAD(0);
  SWRITE(0);
  for (int kt = 0; kt < NTK; ++kt) {
    if (kt + 1 < NTK) GLOAD(kt + 1);
    __syncthreads();
    const char* sb = lds + (kt & 1) * 32768;
#pragma unroll
    for (int ks = 0; ks < 2; ++ks) {
      bf16x8 af[4], bfr[4];
#pragma unroll
      for (int mf = 0; mf < 4; ++mf) {
        int row = wm + mf * 16 + r15;
        int colB = ks * 64 + g16;
        af[mf] = *(const bf16x8*)(sb + row * 128 + (colB ^ ((row & 7) << 4)));
      }
#pragma unroll
      for (int nf = 0; nf < 4; ++nf) {
        int row = wn + nf * 16 + r15;
        int colB = ks * 64 + g16;
        bfr[nf] = *(const bf16x8*)(sb + 16384 + row * 128 + (colB ^ ((row & 7) << 4)));
      }
#pragma unroll
      for (int mf = 0; mf < 4; ++mf)
#pragma unroll
        for (int nf = 0; nf < 4; ++nf)
          acc[mf][nf] =
              __builtin_amdgcn_mfma_f32_16x16x32_bf16(af[mf], bfr[nf], acc[mf][nf], 0, 0, 0);
    }
    if (kt + 1 < NTK) SWRITE((kt + 1) & 1);
  }

  // epilogue: D row m=(lane>>4)*4+r, col n=lane&15 (verified m89 layout), ReLU
#pragma unroll
  for (int mf = 0; mf < 4; ++mf) {
#pragma unroll
    for (int r = 0; r < 4; ++r) {
      int grow = m0 + wm + mf * 16 + (lane >> 4) * 4 + r;
      if (grow >= M) continue;
#pragma unroll
      for (int nf = 0; nf < 4; ++nf) {
        int gcol = n0 + wn + nf * 16 + r15;
        float v = fmaxf(acc[mf][nf][r], 0.f);
        if (OUTF32)
          ((float*)Cout)[(size_t)grow * DD + gcol] = v;
        else
          ((unsigned short*)Cout)[(size_t)grow * DD + gcol] = f2bf(v);
      }
    }
  }
#undef GLOAD
#undef SWRITE
}

extern "C" void kernel_launch(void* const* d_in, const int* in_sizes, int n_in,
                              void* d_out, int out_size, void* d_ws, size_t ws_size,
                              hipStream_t stream) {
  const int* labels = (const int*)d_in[0];
  const int* adj = (const int*)d_in[1];      // [NT][EPT][2]
  const float* emb = (const float*)d_in[2];  // [VOCAB][DD]
  const float* Wl = (const float*)d_in[3];   // [NL][NT][DD][DD]

  // ---- workspace layout (~108.3 MB) ----
  char* base = (char*)d_ws;
  unsigned short* h = (unsigned short*)base;  // bf16 [NN][256], 25.6 MB
  size_t off = (size_t)NN * DD * 2;
  unsigned short* Gcat = (unsigned short*)(base + off);  // bf16 [MROWS][768], 76.9 MB
  off += (size_t)MROWS * KK * 2;
  unsigned short* WT = (unsigned short*)(base + off);  // bf16 [NL][256][768], 1.57 MB
  off += (size_t)NL * DD * KK * 2;
  int* rowptr = (int*)(base + off);
  off += (size_t)((3 * (NN + 1) * 4 + 15) & ~15);
  int* esrc = (int*)(base + off);  // 3*EPT ints, 3.6 MB

  // CSR-build temporaries overlaid on Gcat (not live until first agg)
  int* counts = (int*)Gcat;                          // 3*NN ints
  int* cursor = (int*)((char*)Gcat + (1 << 20));     // +1MB
  int* bsums = (int*)((char*)Gcat + (2 << 20));      // +2MB

  // ---- weight convert (once) + h0 gather ----
  wconv<<<(NL * DD * KK) / 256, 256, 0, stream>>>(Wl, WT);
  gather_emb<<<NN, 64, 0, stream>>>(labels, emb, h);

  // ---- CSR build (once; adjacency shared by all layers) ----
  zero_kernel<<<256, 256, 0, stream>>>((float*)counts, (3 * NN) / 4);
  {
    dim3 g((EPT + 255) / 256, NT);
    hist_kernel<<<g, 256, 0, stream>>>(adj, counts);
  }
  {
    dim3 g(SCAN_BLOCKS, NT);
    scan1<<<g, 256, 0, stream>>>(counts, rowptr, bsums);
  }
  scan2<<<NT, 256, 0, stream>>>(bsums);
  {
    dim3 g(SCAN_BLOCKS, NT);
    scan3<<<g, 256, 0, stream>>>(rowptr, bsums, cursor);
  }
  {
    dim3 g((EPT + 255) / 256, NT);
    bucket_kernel<<<g, 256, 0, stream>>>(adj, cursor, esrc);
  }

  // ---- layers: agg (3 types into Gcat) then one K=768 GEMM ----
  dim3 gg((MROWS) / 128, 2);
  for (int l = 0; l < NL; ++l) {
    for (int t = 0; t < NT; ++t) {
      agg_csr<<<(NN + 3) / 4, 256, 0, stream>>>(
          rowptr + (size_t)t * (NN + 1), esrc + (size_t)t * EPT, h, Gcat, t);
    }
    const unsigned short* WTl = WT + (size_t)l * DD * KK;
    if (l < NL - 1)
      gemm_bf16<0><<<gg, 256, 0, stream>>>(Gcat, WTl, h, NN);
    else
      gemm_bf16<1><<<gg, 256, 0, stream>>>(Gcat, WTl, d_out, NN);
  }
}